// Round 1
// baseline (2249.144 us; speedup 1.0000x reference)
//
#include <hip/hip_runtime.h>

// Problem constants
#define WW 256
#define NB 128      // batch N
#define CD 512      // channels
#define NE 8        // heads
#define HD 64       // head dim
#define WCHUNK 64   // w-chunk size
#define NCHUNKS 4
#define SCALING 0.125f

// workspace layout (float offsets)
#define OFF_MEAN   0u
#define OFF_RSTD   65536u
#define OFF_WP     131072u          // 1536*512
#define OFF_S      917504u          // 1536
#define OFF_U      919040u          // 1536
#define OFF_PQ     920576u          // 511*512 (scaled q_r table)
#define OFF_PK     1182208u         // 511*512 (k_r table)
#define OFF_Q      1443840u         // 32768*512
#define OFF_K      18221056u
#define OFF_V      34998272u
#define OFF_ATTN   51775488u        // 128*8*64*256
#define OFF_T3     68552704u        // 8*256*128*64
#define OFF_VOPRE  85329920u        // 64*128*512
// total 89,524,224 floats = ~358 MB

// ---------------------------------------------------------------------------
// Row stats for LN folding: mean/rstd per row of feat_left (rows 0..32767) and
// feat_right (rows 32768..65535). One wave per row.
__global__ __launch_bounds__(256) void stats_kernel(const float* __restrict__ L,
                                                    const float* __restrict__ R,
                                                    float* __restrict__ mean,
                                                    float* __restrict__ rstd) {
  int wave = threadIdx.x >> 6, lane = threadIdx.x & 63;
  int row = blockIdx.x * 4 + wave;
  const float* src = (row < 32768) ? (L + (size_t)row * CD) : (R + (size_t)(row - 32768) * CD);
  float4 a = *(const float4*)(src + lane * 4);
  float4 b = *(const float4*)(src + 256 + lane * 4);
  float s  = a.x + a.y + a.z + a.w + b.x + b.y + b.z + b.w;
  float ss = a.x*a.x + a.y*a.y + a.z*a.z + a.w*a.w + b.x*b.x + b.y*b.y + b.z*b.z + b.w*b.w;
#pragma unroll
  for (int off = 32; off > 0; off >>= 1) {
    s  += __shfl_xor(s, off);
    ss += __shfl_xor(ss, off);
  }
  if (lane == 0) {
    float m = s * (1.0f / 512.0f);
    float v = ss * (1.0f / 512.0f) - m * m;
    mean[row] = m;
    rstd[row] = rsqrtf(v + 1e-5f);
  }
}

// ---------------------------------------------------------------------------
// Fold ln_w into in_proj_w; compute per-output-row constants S,U.
__global__ __launch_bounds__(256) void prep_kernel(const float* __restrict__ ipw,
                                                   const float* __restrict__ ipb,
                                                   const float* __restrict__ lnw,
                                                   const float* __restrict__ lnb,
                                                   float* __restrict__ Wp,
                                                   float* __restrict__ S,
                                                   float* __restrict__ U) {
  int o = blockIdx.x, t = threadIdx.x;
  float s = 0.f, u = 0.f;
#pragma unroll
  for (int j0 = 0; j0 < 512; j0 += 256) {
    int j = j0 + t;
    float w0 = ipw[(size_t)o * 512 + j];
    float wl = w0 * lnw[j];
    Wp[(size_t)o * 512 + j] = wl;
    s += wl;
    u += w0 * lnb[j];
  }
  __shared__ float rs[4], ru[4];
  int lane = t & 63, wv = t >> 6;
#pragma unroll
  for (int off = 32; off > 0; off >>= 1) { s += __shfl_xor(s, off); u += __shfl_xor(u, off); }
  if (lane == 0) { rs[wv] = s; ru[wv] = u; }
  __syncthreads();
  if (t == 0) {
    S[o] = rs[0] + rs[1] + rs[2] + rs[3];
    U[o] = ru[0] + ru[1] + ru[2] + ru[3] + ipb[o];
  }
}

// ---------------------------------------------------------------------------
// inner-product helpers: LDS tiles stored [k][m] with stride 64.
__device__ __forceinline__ void compute16(const float* __restrict__ As,
                                          const float* __restrict__ Bs,
                                          float acc[4][4], int tx, int ty) {
#pragma unroll
  for (int kk = 0; kk < 16; ++kk) {
    float4 av = *(const float4*)(As + kk * 64 + ty * 4);
    float4 bv = *(const float4*)(Bs + kk * 64 + tx * 4);
    const float aa[4] = {av.x, av.y, av.z, av.w};
    const float bb[4] = {bv.x, bv.y, bv.z, bv.w};
#pragma unroll
    for (int i = 0; i < 4; ++i)
#pragma unroll
      for (int j = 0; j < 4; ++j)
        acc[i][j] = fmaf(aa[i], bb[j], acc[i][j]);
  }
}

__device__ __forceinline__ void compute64(const float* __restrict__ As,
                                          const float* __restrict__ Bs,
                                          float acc[4][4], int tx, int ty) {
#pragma unroll 8
  for (int kk = 0; kk < 64; ++kk) {
    float4 av = *(const float4*)(As + kk * 64 + ty * 4);
    float4 bv = *(const float4*)(Bs + kk * 64 + tx * 4);
    const float aa[4] = {av.x, av.y, av.z, av.w};
    const float bb[4] = {bv.x, bv.y, bv.z, bv.w};
#pragma unroll
    for (int i = 0; i < 4; ++i)
#pragma unroll
      for (int j = 0; j < 4; ++j)
        acc[i][j] = fmaf(aa[i], bb[j], acc[i][j]);
  }
}

// load 64 rows x 64 k (k contiguous in memory) into s[k*64 + row]
__device__ __forceinline__ void load64(float* s, const float* base, int stride, int t) {
  int r = t >> 2, q = t & 3;
  const float4* src = (const float4*)(base + (size_t)r * stride);
#pragma unroll
  for (int f = 0; f < 4; ++f) {
    float4 d = src[q * 4 + f];
    int c = (q * 4 + f) * 4;
    s[(c + 0) * 64 + r] = d.x;
    s[(c + 1) * 64 + r] = d.y;
    s[(c + 2) * 64 + r] = d.z;
    s[(c + 3) * 64 + r] = d.w;
  }
}

// gather variant: row r comes from tbl[idx[idxBase + r*idxStride]*512 + colOff + k]
__device__ __forceinline__ void load64_gather(float* s, const float* __restrict__ tbl,
                                              const int* __restrict__ idx,
                                              int idxBase, int idxStride, int colOff, int t) {
  int r = t >> 2, q = t & 3;
  int ri = idx[idxBase + r * idxStride];
  const float4* src = (const float4*)(tbl + (size_t)ri * 512 + colOff);
#pragma unroll
  for (int f = 0; f < 4; ++f) {
    float4 d = src[q * 4 + f];
    int c = (q * 4 + f) * 4;
    s[(c + 0) * 64 + r] = d.x;
    s[(c + 1) * 64 + r] = d.y;
    s[(c + 2) * 64 + r] = d.z;
    s[(c + 3) * 64 + r] = d.w;
  }
}

// ---------------------------------------------------------------------------
// LN-folded projection GEMM: out[m, o] = ((sum_j X[m,j]*Wp[o,j]) - mean_m*S_o)*rstd_m + U_o, * scale
// grid.x = Nout/64 tiles, grid.y = M/64 tiles. Column tile n0 routed to out0 (n0<512) or out1.
__global__ __launch_bounds__(256) void proj_kernel(const float* __restrict__ X,
                                                   const float* __restrict__ Wp,
                                                   const float* __restrict__ S,
                                                   const float* __restrict__ U,
                                                   const float* __restrict__ mean,
                                                   const float* __restrict__ rstd,
                                                   float* __restrict__ out0,
                                                   float* __restrict__ out1,
                                                   int wOff, int statOff, float scale) {
  __shared__ float As[16 * 64], Bs[16 * 64];
  int t = threadIdx.x, tx = t & 15, ty = t >> 4;
  int n0 = blockIdx.x * 64, m0 = blockIdx.y * 64;
  int lr = t >> 2, lq = t & 3;
  const float* xrow = X + (size_t)(m0 + lr) * 512 + lq * 4;
  const float* wrow = Wp + (size_t)(wOff + n0 + lr) * 512 + lq * 4;
  float acc[4][4] = {};
  for (int kt = 0; kt < 512; kt += 16) {
    float4 a = *(const float4*)(xrow + kt);
    float4 b = *(const float4*)(wrow + kt);
    __syncthreads();
    As[(lq * 4 + 0) * 64 + lr] = a.x; As[(lq * 4 + 1) * 64 + lr] = a.y;
    As[(lq * 4 + 2) * 64 + lr] = a.z; As[(lq * 4 + 3) * 64 + lr] = a.w;
    Bs[(lq * 4 + 0) * 64 + lr] = b.x; Bs[(lq * 4 + 1) * 64 + lr] = b.y;
    Bs[(lq * 4 + 2) * 64 + lr] = b.z; Bs[(lq * 4 + 3) * 64 + lr] = b.w;
    __syncthreads();
    compute16(As, Bs, acc, tx, ty);
  }
  float* dst; int co;
  if (n0 < 512) { dst = out0; co = n0; } else { dst = out1; co = n0 - 512; }
#pragma unroll
  for (int i = 0; i < 4; ++i) {
    int m = m0 + ty * 4 + i;
    float rst = rstd[statOff + m], mn = mean[statOff + m];
    float4 r;
#pragma unroll
    for (int j = 0; j < 4; ++j) {
      int o = wOff + n0 + tx * 4 + j;
      ((float*)&r)[j] = ((acc[i][j] - mn * S[o]) * rst + U[o]) * scale;
    }
    *(float4*)(dst + (size_t)m * 512 + co + tx * 4) = r;
  }
}

// ---------------------------------------------------------------------------
// pos table projection (NO layernorm): Pq/Pk[r, o] = (pos[r] . ipw[o] + ipb[o]) * (o<512 ? 0.125 : 1)
__global__ __launch_bounds__(256) void posproj_kernel(const float* __restrict__ pos,
                                                      const float* __restrict__ ipw,
                                                      const float* __restrict__ ipb,
                                                      float* __restrict__ Pq,
                                                      float* __restrict__ Pk) {
  __shared__ float As[16 * 64], Bs[16 * 64];
  int t = threadIdx.x, tx = t & 15, ty = t >> 4;
  int n0 = blockIdx.x * 64, m0 = blockIdx.y * 64;
  int lr = t >> 2, lq = t & 3;
  int arow = m0 + lr; if (arow > 510) arow = 510;
  const float* xrow = pos + (size_t)arow * 512 + lq * 4;
  const float* wrow = ipw + (size_t)(n0 + lr) * 512 + lq * 4;
  float acc[4][4] = {};
  for (int kt = 0; kt < 512; kt += 16) {
    float4 a = *(const float4*)(xrow + kt);
    float4 b = *(const float4*)(wrow + kt);
    __syncthreads();
    As[(lq * 4 + 0) * 64 + lr] = a.x; As[(lq * 4 + 1) * 64 + lr] = a.y;
    As[(lq * 4 + 2) * 64 + lr] = a.z; As[(lq * 4 + 3) * 64 + lr] = a.w;
    Bs[(lq * 4 + 0) * 64 + lr] = b.x; Bs[(lq * 4 + 1) * 64 + lr] = b.y;
    Bs[(lq * 4 + 2) * 64 + lr] = b.z; Bs[(lq * 4 + 3) * 64 + lr] = b.w;
    __syncthreads();
    compute16(As, Bs, acc, tx, ty);
  }
  float scale = (n0 < 512) ? SCALING : 1.0f;
  float* dst; int co;
  if (n0 < 512) { dst = Pq; co = n0; } else { dst = Pk; co = n0 - 512; }
#pragma unroll
  for (int i = 0; i < 4; ++i) {
    int m = m0 + ty * 4 + i;
    if (m < 511) {
      float4 r;
#pragma unroll
      for (int j = 0; j < 4; ++j)
        ((float*)&r)[j] = (acc[i][j] + ipb[n0 + tx * 4 + j]) * scale;
      *(float4*)(dst + (size_t)m * 512 + co + tx * 4) = r;
    }
  }
}

// ---------------------------------------------------------------------------
// term3: T3[e][v][n][wq] = sum_h k[v,n,e,h] * q_r[wq,v,e,h]   (pure write)
// grid: x=nt(2), y=e(8), z=v(256)
__global__ __launch_bounds__(256) void t3_kernel(const float* __restrict__ kb,
                                                 const float* __restrict__ Pq,
                                                 const int* __restrict__ idx,
                                                 float* __restrict__ T3, int wc) {
  __shared__ float As[64 * 64], Bs[64 * 64];
  int t = threadIdx.x, tx = t & 15, ty = t >> 4;
  int nt = blockIdx.x, e = blockIdx.y, v = blockIdx.z;
  load64(As, kb + ((size_t)v * NB + nt * 64) * CD + e * 64, CD, t);
  load64_gather(Bs, Pq, idx, (wc * 64) * WW + v, WW, e * 64, t);
  __syncthreads();
  float acc[4][4] = {};
  compute64(As, Bs, acc, tx, ty);
#pragma unroll
  for (int i = 0; i < 4; ++i) {
    int n = nt * 64 + ty * 4 + i;
    float4 r = {acc[i][0], acc[i][1], acc[i][2], acc[i][3]};
    *(float4*)(T3 + (((size_t)e * WW + v) * NB + n) * 64 + tx * 4) = r;
  }
}

// ---------------------------------------------------------------------------
// transpose T3 into attn layout (pure write, first writer of attn each chunk):
// attn[n][e][wq][v] = T3[e][v][n][wq]. grid: x=vt(4), y=e(8), z=n(128)
__global__ __launch_bounds__(256) void trans_kernel(const float* __restrict__ T3,
                                                    float* __restrict__ attn) {
  __shared__ float Ts[64 * 65];
  int t = threadIdx.x;
  int vt = blockIdx.x, e = blockIdx.y, n = blockIdx.z;
  int a = t & 63, g = t >> 6;
  const float* src = T3 + (((size_t)e * WW + vt * 64) * NB + n) * 64;
#pragma unroll
  for (int it = 0; it < 16; ++it) {
    int vv = g + it * 4;
    Ts[vv * 65 + a] = src[(size_t)vv * NB * 64 + a];
  }
  __syncthreads();
  float* dst = attn + (((size_t)n * NE + e) * 64) * WW + vt * 64;
#pragma unroll
  for (int it = 0; it < 16; ++it) {
    int wq = g + it * 4;
    dst[(size_t)wq * WW + a] = Ts[a * 65 + wq];
  }
}

// ---------------------------------------------------------------------------
// term1: attn[n,e,wq,v] += sum_h q[wq,n,e,h]*k[v,n,e,h]. grid: x=vt(4), y=e(8), z=n(128)
__global__ __launch_bounds__(256) void t1_kernel(const float* __restrict__ qb,
                                                 const float* __restrict__ kb,
                                                 float* __restrict__ attn, int wc) {
  __shared__ float As[64 * 64], Bs[64 * 64];
  int t = threadIdx.x, tx = t & 15, ty = t >> 4;
  int vt = blockIdx.x, e = blockIdx.y, n = blockIdx.z;
  load64(As, qb + ((size_t)(wc * 64) * NB + n) * CD + e * 64, NB * CD, t);
  load64(Bs, kb + ((size_t)(vt * 64) * NB + n) * CD + e * 64, NB * CD, t);
  __syncthreads();
  float acc[4][4] = {};
  compute64(As, Bs, acc, tx, ty);
  float* cb = attn + (((size_t)n * NE + e) * 64) * WW + vt * 64;
#pragma unroll
  for (int i = 0; i < 4; ++i) {
    float* p4 = cb + (size_t)(ty * 4 + i) * WW + tx * 4;
    float4 old = *(float4*)p4;
    old.x += acc[i][0]; old.y += acc[i][1]; old.z += acc[i][2]; old.w += acc[i][3];
    *(float4*)p4 = old;
  }
}

// ---------------------------------------------------------------------------
// term2: attn[n,e,wq,v] += sum_h q[wq,n,e,h]*k_r[wq,v,e,h]. grid: x=vt(4)+4*nt(2), y=e(8), z=wq(64)
__global__ __launch_bounds__(256) void t2_kernel(const float* __restrict__ qb,
                                                 const float* __restrict__ Pk,
                                                 const int* __restrict__ idx,
                                                 float* __restrict__ attn, int wc) {
  __shared__ float As[64 * 64], Bs[64 * 64];
  int t = threadIdx.x, tx = t & 15, ty = t >> 4;
  int vt = blockIdx.x & 3, nt = blockIdx.x >> 2, e = blockIdx.y, wql = blockIdx.z;
  int wq = wc * 64 + wql;
  load64(As, qb + ((size_t)wq * NB + nt * 64) * CD + e * 64, CD, t);
  load64_gather(Bs, Pk, idx, wq * WW + vt * 64, 1, e * 64, t);
  __syncthreads();
  float acc[4][4] = {};
  compute64(As, Bs, acc, tx, ty);
#pragma unroll
  for (int i = 0; i < 4; ++i) {
    int n = nt * 64 + ty * 4 + i;
    float* p4 = attn + (((size_t)n * NE + e) * 64 + wql) * WW + vt * 64 + tx * 4;
    float4 old = *(float4*)p4;
    old.x += acc[i][0]; old.y += acc[i][1]; old.z += acc[i][2]; old.w += acc[i][3];
    *(float4*)p4 = old;
  }
}

// ---------------------------------------------------------------------------
// raw-sum over e + softmax over v, in place. grid: x=wq(64), y=n(128), 256 thr = v
__device__ __forceinline__ float blk_max(float x, float* red, int t) {
#pragma unroll
  for (int off = 32; off > 0; off >>= 1) x = fmaxf(x, __shfl_xor(x, off));
  __syncthreads();
  if ((t & 63) == 0) red[t >> 6] = x;
  __syncthreads();
  return fmaxf(fmaxf(red[0], red[1]), fmaxf(red[2], red[3]));
}
__device__ __forceinline__ float blk_sum(float x, float* red, int t) {
#pragma unroll
  for (int off = 32; off > 0; off >>= 1) x += __shfl_xor(x, off);
  __syncthreads();
  if ((t & 63) == 0) red[t >> 6] = x;
  __syncthreads();
  return red[0] + red[1] + red[2] + red[3];
}

__global__ __launch_bounds__(256) void soft_kernel(float* __restrict__ attn,
                                                   float* __restrict__ raw, int wc) {
  __shared__ float red[4];
  int t = threadIdx.x;
  int wq = blockIdx.x, n = blockIdx.y;
  float rows[NE]; float rsum = 0.f;
  float* base = attn + (((size_t)n * NE) * 64 + wq) * WW + t;
#pragma unroll
  for (int e = 0; e < NE; ++e) { rows[e] = base[(size_t)e * 64 * WW]; rsum += rows[e]; }
  raw[((size_t)n * WW + wc * 64 + wq) * WW + t] = rsum;
#pragma unroll
  for (int e = 0; e < NE; ++e) {
    float m = blk_max(rows[e], red, t);
    float ex = __expf(rows[e] - m);
    float s = blk_sum(ex, red, t);
    base[(size_t)e * 64 * WW] = ex / s;
  }
}

// ---------------------------------------------------------------------------
// PV: vo[wq][n][e*64+h] = sum_v p[n,e,wq,v] * v[v,n,e,h]. grid: x=e(8), y=n(128)
__global__ __launch_bounds__(256) void pv_kernel(const float* __restrict__ attn,
                                                 const float* __restrict__ vb,
                                                 float* __restrict__ vo) {
  __shared__ float As[16 * 64], Bs[16 * 64];
  int t = threadIdx.x, tx = t & 15, ty = t >> 4;
  int e = blockIdx.x, n = blockIdx.y;
  int lr = t >> 2, lq = t & 3;    // A loader: 64 wq-rows x 16 v
  int bv = t >> 4, bh = t & 15;   // B loader: 16 v-rows x 64 h
  const float* abase = attn + (((size_t)n * NE + e) * 64 + lr) * WW + lq * 4;
  float acc[4][4] = {};
  for (int kt = 0; kt < WW; kt += 16) {
    float4 a = *(const float4*)(abase + kt);
    float4 b = *(const float4*)(vb + ((size_t)(kt + bv) * NB + n) * CD + e * 64 + bh * 4);
    __syncthreads();
    As[(lq * 4 + 0) * 64 + lr] = a.x; As[(lq * 4 + 1) * 64 + lr] = a.y;
    As[(lq * 4 + 2) * 64 + lr] = a.z; As[(lq * 4 + 3) * 64 + lr] = a.w;
    *(float4*)(&Bs[bv * 64 + bh * 4]) = b;
    __syncthreads();
    compute16(As, Bs, acc, tx, ty);
  }
#pragma unroll
  for (int i = 0; i < 4; ++i) {
    float4 r = {acc[i][0], acc[i][1], acc[i][2], acc[i][3]};
    *(float4*)(vo + ((size_t)(ty * 4 + i) * NB + n) * CD + e * 64 + tx * 4) = r;
  }
}

// ---------------------------------------------------------------------------
// out-proj + bias + residual: out[g, o] = fl[g, o] + sum_j vo[m, j]*ow[o, j] + ob[o]
// grid: x = 8 (o tiles), y = 128 (m tiles of chunk's 8192 rows)
__global__ __launch_bounds__(256) void outproj_kernel(const float* __restrict__ vo,
                                                      const float* __restrict__ ow,
                                                      const float* __restrict__ ob,
                                                      const float* __restrict__ fl,
                                                      float* __restrict__ out, int wc) {
  __shared__ float As[16 * 64], Bs[16 * 64];
  int t = threadIdx.x, tx = t & 15, ty = t >> 4;
  int n0 = blockIdx.x * 64, m0 = blockIdx.y * 64;
  int lr = t >> 2, lq = t & 3;
  const float* arow = vo + (size_t)(m0 + lr) * 512 + lq * 4;
  const float* brow = ow + (size_t)(n0 + lr) * 512 + lq * 4;
  float acc[4][4] = {};
  for (int kt = 0; kt < 512; kt += 16) {
    float4 a = *(const float4*)(arow + kt);
    float4 b = *(const float4*)(brow + kt);
    __syncthreads();
    As[(lq * 4 + 0) * 64 + lr] = a.x; As[(lq * 4 + 1) * 64 + lr] = a.y;
    As[(lq * 4 + 2) * 64 + lr] = a.z; As[(lq * 4 + 3) * 64 + lr] = a.w;
    Bs[(lq * 4 + 0) * 64 + lr] = b.x; Bs[(lq * 4 + 1) * 64 + lr] = b.y;
    Bs[(lq * 4 + 2) * 64 + lr] = b.z; Bs[(lq * 4 + 3) * 64 + lr] = b.w;
    __syncthreads();
    compute16(As, Bs, acc, tx, ty);
  }
  size_t gbase = (size_t)wc * 64 * NB * CD;
#pragma unroll
  for (int i = 0; i < 4; ++i) {
    int m = m0 + ty * 4 + i;
    size_t go = gbase + (size_t)m * 512 + n0 + tx * 4;
    float4 res = *(const float4*)(fl + go);
    float4 r;
    r.x = acc[i][0] + ob[n0 + tx * 4 + 0] + res.x;
    r.y = acc[i][1] + ob[n0 + tx * 4 + 1] + res.y;
    r.z = acc[i][2] + ob[n0 + tx * 4 + 2] + res.z;
    r.w = acc[i][3] + ob[n0 + tx * 4 + 3] + res.w;
    *(float4*)(out + go) = r;
  }
}

// ---------------------------------------------------------------------------
extern "C" void kernel_launch(void* const* d_in, const int* in_sizes, int n_in,
                              void* d_out, int out_size, void* d_ws, size_t ws_size,
                              hipStream_t stream) {
  const float* fl  = (const float*)d_in[0];
  const float* fr  = (const float*)d_in[1];
  const float* pos = (const float*)d_in[2];
  const int*  pidx = (const int*)d_in[3];
  const float* lnw = (const float*)d_in[4];
  const float* lnb = (const float*)d_in[5];
  const float* ipw = (const float*)d_in[6];
  const float* ipb = (const float*)d_in[7];
  const float* ow  = (const float*)d_in[8];
  const float* ob  = (const float*)d_in[9];

  float* ws   = (float*)d_ws;
  float* mean = ws + OFF_MEAN;
  float* rstd = ws + OFF_RSTD;
  float* Wp   = ws + OFF_WP;
  float* S    = ws + OFF_S;
  float* U    = ws + OFF_U;
  float* Pq   = ws + OFF_PQ;
  float* Pk   = ws + OFF_PK;
  float* qb   = ws + OFF_Q;
  float* kb   = ws + OFF_K;
  float* vb   = ws + OFF_V;
  float* attn = ws + OFF_ATTN;
  float* T3   = ws + OFF_T3;
  float* vo   = ws + OFF_VOPRE;

  float* outF = (float*)d_out;                       // [W][N][C]
  float* outR = outF + (size_t)WW * NB * CD;         // raw_attn [N][W][W]

  stats_kernel<<<16384, 256, 0, stream>>>(fl, fr, mean, rstd);
  prep_kernel<<<1536, 256, 0, stream>>>(ipw, ipb, lnw, lnb, Wp, S, U);
  posproj_kernel<<<dim3(16, 8), 256, 0, stream>>>(pos, ipw, ipb, Pq, Pk);
  proj_kernel<<<dim3(8, 512), 256, 0, stream>>>(fl, Wp, S, U, mean, rstd, qb, qb, 0, 0, SCALING);
  proj_kernel<<<dim3(16, 512), 256, 0, stream>>>(fr, Wp, S, U, mean, rstd, kb, vb, 512, 32768, 1.0f);

  for (int wc = 0; wc < NCHUNKS; ++wc) {
    t3_kernel<<<dim3(2, 8, 256), 256, 0, stream>>>(kb, Pq, pidx, T3, wc);
    trans_kernel<<<dim3(4, 8, 128), 256, 0, stream>>>(T3, attn);
    t1_kernel<<<dim3(4, 8, 128), 256, 0, stream>>>(qb, kb, attn, wc);
    t2_kernel<<<dim3(8, 8, 64), 256, 0, stream>>>(qb, Pk, pidx, attn, wc);
    soft_kernel<<<dim3(64, 128), 256, 0, stream>>>(attn, outR, wc);
    pv_kernel<<<dim3(8, 128), 256, 0, stream>>>(attn, vb, vo);
    outproj_kernel<<<dim3(8, 128), 256, 0, stream>>>(vo, ow, ob, fl, outF, wc);
  }
}

// Round 2
// 1347.320 us; speedup vs baseline: 1.6693x; 1.6693x over previous
//
#include <hip/hip_runtime.h>

// Problem constants
#define WW 256
#define NB 128      // batch N
#define CD 512      // channels
#define NE 8        // heads
#define HD 64       // head dim
#define WCHUNK 64   // w-chunk size
#define NCHUNKS 4
#define SCALING 0.125f

typedef __attribute__((ext_vector_type(8))) short bfx8;
typedef __attribute__((ext_vector_type(4))) float fx4;

// workspace layout (float offsets)
#define OFF_MEAN   0u
#define OFF_RSTD   65536u
#define OFF_WPB    131072u          // 1536*512 bf16 (shorts) -> 393216 floats
#define OFF_OWB    524288u          // 512*512 bf16 -> 131072 floats
#define OFF_S      655360u
#define OFF_U      656896u
#define OFF_PQ     658432u          // 511*512 fp32 (scaled q_r table)
#define OFF_PK     920064u          // 511*512 fp32 (k_r table)
#define OFF_Q      1181696u         // 32768*512 fp32
#define OFF_K      17958912u
#define OFF_V      34736128u
#define OFF_ATTN   51513344u        // 128*8*64*256 fp32 (flb bf16 overlaid pre-loop)
#define OFF_T3     68290560u        // 8*256*128*64 fp32 (frb bf16 overlaid pre-loop)
#define OFF_VOB    85067776u        // 64*128*512 bf16
// total 87,164,928 floats = ~349 MB

// ---------------------------------------------------------------------------
__device__ __forceinline__ unsigned short f2bf(float f) {
  unsigned u = __builtin_bit_cast(unsigned, f);
  u = (u + 0x7fffu + ((u >> 16) & 1u)) >> 16;
  return (unsigned short)u;
}
__device__ __forceinline__ float bf2f(unsigned short h) {
  unsigned u = ((unsigned)h) << 16;
  return __builtin_bit_cast(float, u);
}

#define GLDS16(g, l)                                                          \
  __builtin_amdgcn_global_load_lds(                                           \
      (const __attribute__((address_space(1))) void*)(g),                     \
      (__attribute__((address_space(3))) void*)(l), 16, 0, 0)

// ---------------------------------------------------------------------------
// fp32 -> bf16 convert, 8 elements/thread
__global__ __launch_bounds__(256) void cvt_kernel(const float* __restrict__ a,
                                                  unsigned short* __restrict__ b,
                                                  int n8) {
  int i = blockIdx.x * 256 + threadIdx.x;
  if (i >= n8) return;
  float4 x = ((const float4*)a)[2 * i];
  float4 y = ((const float4*)a)[2 * i + 1];
  int4 o;
  o.x = (int)(((unsigned)f2bf(x.y) << 16) | f2bf(x.x));
  o.y = (int)(((unsigned)f2bf(x.w) << 16) | f2bf(x.z));
  o.z = (int)(((unsigned)f2bf(y.y) << 16) | f2bf(y.x));
  o.w = (int)(((unsigned)f2bf(y.w) << 16) | f2bf(y.z));
  ((int4*)b)[i] = o;
}

// ---------------------------------------------------------------------------
// Row stats for LN folding (unchanged)
__global__ __launch_bounds__(256) void stats_kernel(const float* __restrict__ L,
                                                    const float* __restrict__ R,
                                                    float* __restrict__ mean,
                                                    float* __restrict__ rstd) {
  int wave = threadIdx.x >> 6, lane = threadIdx.x & 63;
  int row = blockIdx.x * 4 + wave;
  const float* src = (row < 32768) ? (L + (size_t)row * CD) : (R + (size_t)(row - 32768) * CD);
  float4 a = *(const float4*)(src + lane * 4);
  float4 b = *(const float4*)(src + 256 + lane * 4);
  float s  = a.x + a.y + a.z + a.w + b.x + b.y + b.z + b.w;
  float ss = a.x*a.x + a.y*a.y + a.z*a.z + a.w*a.w + b.x*b.x + b.y*b.y + b.z*b.z + b.w*b.w;
#pragma unroll
  for (int off = 32; off > 0; off >>= 1) {
    s  += __shfl_xor(s, off);
    ss += __shfl_xor(ss, off);
  }
  if (lane == 0) {
    float m = s * (1.0f / 512.0f);
    float v = ss * (1.0f / 512.0f) - m * m;
    mean[row] = m;
    rstd[row] = rsqrtf(v + 1e-5f);
  }
}

// ---------------------------------------------------------------------------
// Fold ln_w into in_proj_w (bf16 output); per-output-row constants S,U.
__global__ __launch_bounds__(256) void prep_kernel(const float* __restrict__ ipw,
                                                   const float* __restrict__ ipb,
                                                   const float* __restrict__ lnw,
                                                   const float* __restrict__ lnb,
                                                   unsigned short* __restrict__ Wpb,
                                                   float* __restrict__ S,
                                                   float* __restrict__ U) {
  int o = blockIdx.x, t = threadIdx.x;
  float s = 0.f, u = 0.f;
#pragma unroll
  for (int j0 = 0; j0 < 512; j0 += 256) {
    int j = j0 + t;
    float w0 = ipw[(size_t)o * 512 + j];
    float wl = w0 * lnw[j];
    unsigned short h = f2bf(wl);
    Wpb[(size_t)o * 512 + j] = h;
    s += bf2f(h);              // S must match the bf16 weights actually used
    u += w0 * lnb[j];
  }
  __shared__ float rs[4], ru[4];
  int lane = t & 63, wv = t >> 6;
#pragma unroll
  for (int off = 32; off > 0; off >>= 1) { s += __shfl_xor(s, off); u += __shfl_xor(u, off); }
  if (lane == 0) { rs[wv] = s; ru[wv] = u; }
  __syncthreads();
  if (t == 0) {
    S[o] = rs[0] + rs[1] + rs[2] + rs[3];
    U[o] = ru[0] + ru[1] + ru[2] + ru[3] + ipb[o];
  }
}

// ---------------------------------------------------------------------------
// bf16 MFMA GEMM with LN-fold epilogue.
// out[m, o] = ((sum_j Xbf[m,j]*Wpb[o,j]) - mean_m*S_o)*rstd_m + U_o, * scale
// 128x128 tile, BK=32, global_load_lds staging, 4 waves each 64x64.
__global__ __launch_bounds__(256) void gemm_ln(const unsigned short* __restrict__ A,
                                               const unsigned short* __restrict__ Bw,
                                               const float* __restrict__ S,
                                               const float* __restrict__ U,
                                               const float* __restrict__ mean,
                                               const float* __restrict__ rstd,
                                               float* __restrict__ out0,
                                               float* __restrict__ out1,
                                               int wOff, int statOff, float scale) {
  __shared__ unsigned short As[128 * 32];
  __shared__ unsigned short Bs[128 * 32];
  int t = threadIdx.x;
  int lane = t & 63, w = t >> 6;
  int quad = lane >> 4, l15 = lane & 15;
  int wm = w >> 1, wn = w & 1;
  int n0 = blockIdx.x * 128, m0 = blockIdx.y * 128;

  unsigned short* ldsA0 = As + (size_t)w * 16 * 32;
  unsigned short* ldsA1 = As + (size_t)(64 + w * 16) * 32;
  unsigned short* ldsB0 = Bs + (size_t)w * 16 * 32;
  unsigned short* ldsB1 = Bs + (size_t)(64 + w * 16) * 32;
  const unsigned short* gA0 = A + (size_t)(m0 + w * 16 + (lane >> 2)) * 512 + (lane & 3) * 8;
  const unsigned short* gA1 = gA0 + (size_t)64 * 512;
  const unsigned short* gB0 = Bw + (size_t)(wOff + n0 + w * 16 + (lane >> 2)) * 512 + (lane & 3) * 8;
  const unsigned short* gB1 = gB0 + (size_t)64 * 512;

  fx4 acc[4][4];
#pragma unroll
  for (int i = 0; i < 4; ++i)
#pragma unroll
    for (int j = 0; j < 4; ++j) acc[i][j] = (fx4){0.f, 0.f, 0.f, 0.f};

  for (int kt = 0; kt < 512; kt += 32) {
    GLDS16(gA0 + kt, ldsA0);
    GLDS16(gA1 + kt, ldsA1);
    GLDS16(gB0 + kt, ldsB0);
    GLDS16(gB1 + kt, ldsB1);
    __syncthreads();
    bfx8 af[4], bfr[4];
#pragma unroll
    for (int i = 0; i < 4; ++i)
      af[i] = *(const bfx8*)(As + (size_t)(wm * 64 + i * 16 + l15) * 32 + quad * 8);
#pragma unroll
    for (int j = 0; j < 4; ++j)
      bfr[j] = *(const bfx8*)(Bs + (size_t)(wn * 64 + j * 16 + l15) * 32 + quad * 8);
#pragma unroll
    for (int i = 0; i < 4; ++i)
#pragma unroll
      for (int j = 0; j < 4; ++j)
        acc[i][j] = __builtin_amdgcn_mfma_f32_16x16x32_bf16(af[i], bfr[j], acc[i][j], 0, 0, 0);
    __syncthreads();
  }

  // epilogue: LN fold
  float mn[16], rs[16];
#pragma unroll
  for (int i = 0; i < 4; ++i)
#pragma unroll
    for (int r = 0; r < 4; ++r) {
      int m = statOff + m0 + wm * 64 + i * 16 + quad * 4 + r;
      mn[i * 4 + r] = mean[m];
      rs[i * 4 + r] = rstd[m];
    }
#pragma unroll
  for (int j = 0; j < 4; ++j) {
    int oc = n0 + wn * 64 + j * 16 + l15;
    int o = wOff + oc;
    float Sv = S[o], Uv = U[o];
    float* dst; int cc;
    if (oc < 512) { dst = out0; cc = oc; } else { dst = out1; cc = oc - 512; }
#pragma unroll
    for (int i = 0; i < 4; ++i)
#pragma unroll
      for (int r = 0; r < 4; ++r) {
        int m = m0 + wm * 64 + i * 16 + quad * 4 + r;
        dst[(size_t)m * 512 + cc] = ((acc[i][j][r] - mn[i * 4 + r] * Sv) * rs[i * 4 + r] + Uv) * scale;
      }
  }
}

// ---------------------------------------------------------------------------
// bf16 MFMA GEMM out-proj: out[g,o] = fl[g,o] + sum_j vob[m,j]*owb[o,j] + ob[o]
__global__ __launch_bounds__(256) void gemm_out(const unsigned short* __restrict__ A,
                                                const unsigned short* __restrict__ Bw,
                                                const float* __restrict__ ob,
                                                const float* __restrict__ fl,
                                                float* __restrict__ out, int wc) {
  __shared__ unsigned short As[128 * 32];
  __shared__ unsigned short Bs[128 * 32];
  int t = threadIdx.x;
  int lane = t & 63, w = t >> 6;
  int quad = lane >> 4, l15 = lane & 15;
  int wm = w >> 1, wn = w & 1;
  int n0 = blockIdx.x * 128, m0 = blockIdx.y * 128;

  unsigned short* ldsA0 = As + (size_t)w * 16 * 32;
  unsigned short* ldsA1 = As + (size_t)(64 + w * 16) * 32;
  unsigned short* ldsB0 = Bs + (size_t)w * 16 * 32;
  unsigned short* ldsB1 = Bs + (size_t)(64 + w * 16) * 32;
  const unsigned short* gA0 = A + (size_t)(m0 + w * 16 + (lane >> 2)) * 512 + (lane & 3) * 8;
  const unsigned short* gA1 = gA0 + (size_t)64 * 512;
  const unsigned short* gB0 = Bw + (size_t)(n0 + w * 16 + (lane >> 2)) * 512 + (lane & 3) * 8;
  const unsigned short* gB1 = gB0 + (size_t)64 * 512;

  fx4 acc[4][4];
#pragma unroll
  for (int i = 0; i < 4; ++i)
#pragma unroll
    for (int j = 0; j < 4; ++j) acc[i][j] = (fx4){0.f, 0.f, 0.f, 0.f};

  for (int kt = 0; kt < 512; kt += 32) {
    GLDS16(gA0 + kt, ldsA0);
    GLDS16(gA1 + kt, ldsA1);
    GLDS16(gB0 + kt, ldsB0);
    GLDS16(gB1 + kt, ldsB1);
    __syncthreads();
    bfx8 af[4], bfr[4];
#pragma unroll
    for (int i = 0; i < 4; ++i)
      af[i] = *(const bfx8*)(As + (size_t)(wm * 64 + i * 16 + l15) * 32 + quad * 8);
#pragma unroll
    for (int j = 0; j < 4; ++j)
      bfr[j] = *(const bfx8*)(Bs + (size_t)(wn * 64 + j * 16 + l15) * 32 + quad * 8);
#pragma unroll
    for (int i = 0; i < 4; ++i)
#pragma unroll
      for (int j = 0; j < 4; ++j)
        acc[i][j] = __builtin_amdgcn_mfma_f32_16x16x32_bf16(af[i], bfr[j], acc[i][j], 0, 0, 0);
    __syncthreads();
  }

  size_t gbase = (size_t)wc * 64 * NB * CD;
#pragma unroll
  for (int j = 0; j < 4; ++j) {
    int o = n0 + wn * 64 + j * 16 + l15;
    float bias = ob[o];
#pragma unroll
    for (int i = 0; i < 4; ++i)
#pragma unroll
      for (int r = 0; r < 4; ++r) {
        int m = m0 + wm * 64 + i * 16 + quad * 4 + r;
        size_t go = gbase + (size_t)m * 512 + o;
        out[go] = acc[i][j][r] + bias + fl[go];
      }
  }
}

// ---------------------------------------------------------------------------
// fp32 inner-product helpers (unchanged, used by pos/t/pv kernels)
__device__ __forceinline__ void compute16(const float* __restrict__ As,
                                          const float* __restrict__ Bs,
                                          float acc[4][4], int tx, int ty) {
#pragma unroll
  for (int kk = 0; kk < 16; ++kk) {
    float4 av = *(const float4*)(As + kk * 64 + ty * 4);
    float4 bv = *(const float4*)(Bs + kk * 64 + tx * 4);
    const float aa[4] = {av.x, av.y, av.z, av.w};
    const float bb[4] = {bv.x, bv.y, bv.z, bv.w};
#pragma unroll
    for (int i = 0; i < 4; ++i)
#pragma unroll
      for (int j = 0; j < 4; ++j)
        acc[i][j] = fmaf(aa[i], bb[j], acc[i][j]);
  }
}

__device__ __forceinline__ void compute64(const float* __restrict__ As,
                                          const float* __restrict__ Bs,
                                          float acc[4][4], int tx, int ty) {
#pragma unroll 8
  for (int kk = 0; kk < 64; ++kk) {
    float4 av = *(const float4*)(As + kk * 64 + ty * 4);
    float4 bv = *(const float4*)(Bs + kk * 64 + tx * 4);
    const float aa[4] = {av.x, av.y, av.z, av.w};
    const float bb[4] = {bv.x, bv.y, bv.z, bv.w};
#pragma unroll
    for (int i = 0; i < 4; ++i)
#pragma unroll
      for (int j = 0; j < 4; ++j)
        acc[i][j] = fmaf(aa[i], bb[j], acc[i][j]);
  }
}

__device__ __forceinline__ void load64(float* s, const float* base, int stride, int t) {
  int r = t >> 2, q = t & 3;
  const float4* src = (const float4*)(base + (size_t)r * stride);
#pragma unroll
  for (int f = 0; f < 4; ++f) {
    float4 d = src[q * 4 + f];
    int c = (q * 4 + f) * 4;
    s[(c + 0) * 64 + r] = d.x;
    s[(c + 1) * 64 + r] = d.y;
    s[(c + 2) * 64 + r] = d.z;
    s[(c + 3) * 64 + r] = d.w;
  }
}

__device__ __forceinline__ void load64_gather(float* s, const float* __restrict__ tbl,
                                              const int* __restrict__ idx,
                                              int idxBase, int idxStride, int colOff, int t) {
  int r = t >> 2, q = t & 3;
  int ri = idx[idxBase + r * idxStride];
  const float4* src = (const float4*)(tbl + (size_t)ri * 512 + colOff);
#pragma unroll
  for (int f = 0; f < 4; ++f) {
    float4 d = src[q * 4 + f];
    int c = (q * 4 + f) * 4;
    s[(c + 0) * 64 + r] = d.x;
    s[(c + 1) * 64 + r] = d.y;
    s[(c + 2) * 64 + r] = d.z;
    s[(c + 3) * 64 + r] = d.w;
  }
}

// ---------------------------------------------------------------------------
// pos table projection (NO layernorm) — fp32, tiny (0.54 GF)
__global__ __launch_bounds__(256) void posproj_kernel(const float* __restrict__ pos,
                                                      const float* __restrict__ ipw,
                                                      const float* __restrict__ ipb,
                                                      float* __restrict__ Pq,
                                                      float* __restrict__ Pk) {
  __shared__ float As[16 * 64], Bs[16 * 64];
  int t = threadIdx.x, tx = t & 15, ty = t >> 4;
  int n0 = blockIdx.x * 64, m0 = blockIdx.y * 64;
  int lr = t >> 2, lq = t & 3;
  int arow = m0 + lr; if (arow > 510) arow = 510;
  const float* xrow = pos + (size_t)arow * 512 + lq * 4;
  const float* wrow = ipw + (size_t)(n0 + lr) * 512 + lq * 4;
  float acc[4][4] = {};
  for (int kt = 0; kt < 512; kt += 16) {
    float4 a = *(const float4*)(xrow + kt);
    float4 b = *(const float4*)(wrow + kt);
    __syncthreads();
    As[(lq * 4 + 0) * 64 + lr] = a.x; As[(lq * 4 + 1) * 64 + lr] = a.y;
    As[(lq * 4 + 2) * 64 + lr] = a.z; As[(lq * 4 + 3) * 64 + lr] = a.w;
    Bs[(lq * 4 + 0) * 64 + lr] = b.x; Bs[(lq * 4 + 1) * 64 + lr] = b.y;
    Bs[(lq * 4 + 2) * 64 + lr] = b.z; Bs[(lq * 4 + 3) * 64 + lr] = b.w;
    __syncthreads();
    compute16(As, Bs, acc, tx, ty);
  }
  float scale = (n0 < 512) ? SCALING : 1.0f;
  float* dst; int co;
  if (n0 < 512) { dst = Pq; co = n0; } else { dst = Pk; co = n0 - 512; }
#pragma unroll
  for (int i = 0; i < 4; ++i) {
    int m = m0 + ty * 4 + i;
    if (m < 511) {
      float4 r;
#pragma unroll
      for (int j = 0; j < 4; ++j)
        ((float*)&r)[j] = (acc[i][j] + ipb[n0 + tx * 4 + j]) * scale;
      *(float4*)(dst + (size_t)m * 512 + co + tx * 4) = r;
    }
  }
}

// ---------------------------------------------------------------------------
// term3: T3[e][v][n][wq] = sum_h k[v,n,e,h] * q_r[wq,v,e,h]
__global__ __launch_bounds__(256) void t3_kernel(const float* __restrict__ kb,
                                                 const float* __restrict__ Pq,
                                                 const int* __restrict__ idx,
                                                 float* __restrict__ T3, int wc) {
  __shared__ float As[64 * 64], Bs[64 * 64];
  int t = threadIdx.x, tx = t & 15, ty = t >> 4;
  int nt = blockIdx.x, e = blockIdx.y, v = blockIdx.z;
  load64(As, kb + ((size_t)v * NB + nt * 64) * CD + e * 64, CD, t);
  load64_gather(Bs, Pq, idx, (wc * 64) * WW + v, WW, e * 64, t);
  __syncthreads();
  float acc[4][4] = {};
  compute64(As, Bs, acc, tx, ty);
#pragma unroll
  for (int i = 0; i < 4; ++i) {
    int n = nt * 64 + ty * 4 + i;
    float4 r = {acc[i][0], acc[i][1], acc[i][2], acc[i][3]};
    *(float4*)(T3 + (((size_t)e * WW + v) * NB + n) * 64 + tx * 4) = r;
  }
}

// ---------------------------------------------------------------------------
// transpose T3 into attn layout
__global__ __launch_bounds__(256) void trans_kernel(const float* __restrict__ T3,
                                                    float* __restrict__ attn) {
  __shared__ float Ts[64 * 65];
  int t = threadIdx.x;
  int vt = blockIdx.x, e = blockIdx.y, n = blockIdx.z;
  int a = t & 63, g = t >> 6;
  const float* src = T3 + (((size_t)e * WW + vt * 64) * NB + n) * 64;
#pragma unroll
  for (int it = 0; it < 16; ++it) {
    int vv = g + it * 4;
    Ts[vv * 65 + a] = src[(size_t)vv * NB * 64 + a];
  }
  __syncthreads();
  float* dst = attn + (((size_t)n * NE + e) * 64) * WW + vt * 64;
#pragma unroll
  for (int it = 0; it < 16; ++it) {
    int wq = g + it * 4;
    dst[(size_t)wq * WW + a] = Ts[a * 65 + wq];
  }
}

// ---------------------------------------------------------------------------
// term1
__global__ __launch_bounds__(256) void t1_kernel(const float* __restrict__ qb,
                                                 const float* __restrict__ kb,
                                                 float* __restrict__ attn, int wc) {
  __shared__ float As[64 * 64], Bs[64 * 64];
  int t = threadIdx.x, tx = t & 15, ty = t >> 4;
  int vt = blockIdx.x, e = blockIdx.y, n = blockIdx.z;
  load64(As, qb + ((size_t)(wc * 64) * NB + n) * CD + e * 64, NB * CD, t);
  load64(Bs, kb + ((size_t)(vt * 64) * NB + n) * CD + e * 64, NB * CD, t);
  __syncthreads();
  float acc[4][4] = {};
  compute64(As, Bs, acc, tx, ty);
  float* cb = attn + (((size_t)n * NE + e) * 64) * WW + vt * 64;
#pragma unroll
  for (int i = 0; i < 4; ++i) {
    float* p4 = cb + (size_t)(ty * 4 + i) * WW + tx * 4;
    float4 old = *(float4*)p4;
    old.x += acc[i][0]; old.y += acc[i][1]; old.z += acc[i][2]; old.w += acc[i][3];
    *(float4*)p4 = old;
  }
}

// ---------------------------------------------------------------------------
// term2
__global__ __launch_bounds__(256) void t2_kernel(const float* __restrict__ qb,
                                                 const float* __restrict__ Pk,
                                                 const int* __restrict__ idx,
                                                 float* __restrict__ attn, int wc) {
  __shared__ float As[64 * 64], Bs[64 * 64];
  int t = threadIdx.x, tx = t & 15, ty = t >> 4;
  int vt = blockIdx.x & 3, nt = blockIdx.x >> 2, e = blockIdx.y, wql = blockIdx.z;
  int wq = wc * 64 + wql;
  load64(As, qb + ((size_t)wq * NB + nt * 64) * CD + e * 64, CD, t);
  load64_gather(Bs, Pk, idx, wq * WW + vt * 64, 1, e * 64, t);
  __syncthreads();
  float acc[4][4] = {};
  compute64(As, Bs, acc, tx, ty);
#pragma unroll
  for (int i = 0; i < 4; ++i) {
    int n = nt * 64 + ty * 4 + i;
    float* p4 = attn + (((size_t)n * NE + e) * 64 + wql) * WW + vt * 64 + tx * 4;
    float4 old = *(float4*)p4;
    old.x += acc[i][0]; old.y += acc[i][1]; old.z += acc[i][2]; old.w += acc[i][3];
    *(float4*)p4 = old;
  }
}

// ---------------------------------------------------------------------------
// raw-sum over e + softmax over v, in place
__device__ __forceinline__ float blk_max(float x, float* red, int t) {
#pragma unroll
  for (int off = 32; off > 0; off >>= 1) x = fmaxf(x, __shfl_xor(x, off));
  __syncthreads();
  if ((t & 63) == 0) red[t >> 6] = x;
  __syncthreads();
  return fmaxf(fmaxf(red[0], red[1]), fmaxf(red[2], red[3]));
}
__device__ __forceinline__ float blk_sum(float x, float* red, int t) {
#pragma unroll
  for (int off = 32; off > 0; off >>= 1) x += __shfl_xor(x, off);
  __syncthreads();
  if ((t & 63) == 0) red[t >> 6] = x;
  __syncthreads();
  return red[0] + red[1] + red[2] + red[3];
}

__global__ __launch_bounds__(256) void soft_kernel(float* __restrict__ attn,
                                                   float* __restrict__ raw, int wc) {
  __shared__ float red[4];
  int t = threadIdx.x;
  int wq = blockIdx.x, n = blockIdx.y;
  float rows[NE]; float rsum = 0.f;
  float* base = attn + (((size_t)n * NE) * 64 + wq) * WW + t;
#pragma unroll
  for (int e = 0; e < NE; ++e) { rows[e] = base[(size_t)e * 64 * WW]; rsum += rows[e]; }
  raw[((size_t)n * WW + wc * 64 + wq) * WW + t] = rsum;
#pragma unroll
  for (int e = 0; e < NE; ++e) {
    float m = blk_max(rows[e], red, t);
    float ex = __expf(rows[e] - m);
    float s = blk_sum(ex, red, t);
    base[(size_t)e * 64 * WW] = ex / s;
  }
}

// ---------------------------------------------------------------------------
// PV: vob[wq][n][e*64+h] (bf16) = sum_v p[n,e,wq,v] * v[v,n,e,h]
__global__ __launch_bounds__(256) void pv_kernel(const float* __restrict__ attn,
                                                 const float* __restrict__ vb,
                                                 unsigned short* __restrict__ vob) {
  __shared__ float As[16 * 64], Bs[16 * 64];
  int t = threadIdx.x, tx = t & 15, ty = t >> 4;
  int e = blockIdx.x, n = blockIdx.y;
  int lr = t >> 2, lq = t & 3;
  int bv = t >> 4, bh = t & 15;
  const float* abase = attn + (((size_t)n * NE + e) * 64 + lr) * WW + lq * 4;
  float acc[4][4] = {};
  for (int kt = 0; kt < WW; kt += 16) {
    float4 a = *(const float4*)(abase + kt);
    float4 b = *(const float4*)(vb + ((size_t)(kt + bv) * NB + n) * CD + e * 64 + bh * 4);
    __syncthreads();
    As[(lq * 4 + 0) * 64 + lr] = a.x; As[(lq * 4 + 1) * 64 + lr] = a.y;
    As[(lq * 4 + 2) * 64 + lr] = a.z; As[(lq * 4 + 3) * 64 + lr] = a.w;
    *(float4*)(&Bs[bv * 64 + bh * 4]) = b;
    __syncthreads();
    compute16(As, Bs, acc, tx, ty);
  }
#pragma unroll
  for (int i = 0; i < 4; ++i) {
    short4 r;
    r.x = (short)f2bf(acc[i][0]);
    r.y = (short)f2bf(acc[i][1]);
    r.z = (short)f2bf(acc[i][2]);
    r.w = (short)f2bf(acc[i][3]);
    *(short4*)(vob + ((size_t)(ty * 4 + i) * NB + n) * CD + e * 64 + tx * 4) = r;
  }
}

// ---------------------------------------------------------------------------
extern "C" void kernel_launch(void* const* d_in, const int* in_sizes, int n_in,
                              void* d_out, int out_size, void* d_ws, size_t ws_size,
                              hipStream_t stream) {
  const float* fl  = (const float*)d_in[0];
  const float* fr  = (const float*)d_in[1];
  const float* pos = (const float*)d_in[2];
  const int*  pidx = (const int*)d_in[3];
  const float* lnw = (const float*)d_in[4];
  const float* lnb = (const float*)d_in[5];
  const float* ipw = (const float*)d_in[6];
  const float* ipb = (const float*)d_in[7];
  const float* ow  = (const float*)d_in[8];
  const float* ob  = (const float*)d_in[9];

  float* ws   = (float*)d_ws;
  float* mean = ws + OFF_MEAN;
  float* rstd = ws + OFF_RSTD;
  unsigned short* Wpb = (unsigned short*)(ws + OFF_WPB);
  unsigned short* owb = (unsigned short*)(ws + OFF_OWB);
  float* S    = ws + OFF_S;
  float* U    = ws + OFF_U;
  float* Pq   = ws + OFF_PQ;
  float* Pk   = ws + OFF_PK;
  float* qb   = ws + OFF_Q;
  float* kb   = ws + OFF_K;
  float* vb   = ws + OFF_V;
  float* attn = ws + OFF_ATTN;
  float* T3   = ws + OFF_T3;
  unsigned short* vob = (unsigned short*)(ws + OFF_VOB);
  // bf16 staging overlays (consumed before the chunk loop writes attn/T3)
  unsigned short* flb = (unsigned short*)(ws + OFF_ATTN);
  unsigned short* frb = (unsigned short*)(ws + OFF_T3);

  float* outF = (float*)d_out;                       // [W][N][C]
  float* outR = outF + (size_t)WW * NB * CD;         // raw_attn [N][W][W]

  stats_kernel<<<16384, 256, 0, stream>>>(fl, fr, mean, rstd);
  prep_kernel<<<1536, 256, 0, stream>>>(ipw, ipb, lnw, lnb, Wpb, S, U);
  cvt_kernel<<<8192, 256, 0, stream>>>(fl, flb, 2097152);
  cvt_kernel<<<8192, 256, 0, stream>>>(fr, frb, 2097152);
  cvt_kernel<<<128, 256, 0, stream>>>(ow, owb, 32768);
  posproj_kernel<<<dim3(16, 8), 256, 0, stream>>>(pos, ipw, ipb, Pq, Pk);
  // q = LN(fl) @ Wp[:512]^T * 0.125 ; k,v = LN(fr) @ Wp[512:]^T
  gemm_ln<<<dim3(4, 256), 256, 0, stream>>>(flb, Wpb, S, U, mean, rstd, qb, qb, 0, 0, SCALING);
  gemm_ln<<<dim3(8, 256), 256, 0, stream>>>(frb, Wpb, S, U, mean, rstd, kb, vb, 512, 32768, 1.0f);

  for (int wc = 0; wc < NCHUNKS; ++wc) {
    t3_kernel<<<dim3(2, 8, 256), 256, 0, stream>>>(kb, Pq, pidx, T3, wc);
    trans_kernel<<<dim3(4, 8, 128), 256, 0, stream>>>(T3, attn);
    t1_kernel<<<dim3(4, 8, 128), 256, 0, stream>>>(qb, kb, attn, wc);
    t2_kernel<<<dim3(8, 8, 64), 256, 0, stream>>>(qb, Pk, pidx, attn, wc);
    soft_kernel<<<dim3(64, 128), 256, 0, stream>>>(attn, outR, wc);
    pv_kernel<<<dim3(8, 128), 256, 0, stream>>>(attn, vb, vob);
    gemm_out<<<dim3(4, 64), 256, 0, stream>>>(vob, owb, ob, fl, outF, wc);
  }
}

// Round 3
// 1097.705 us; speedup vs baseline: 2.0490x; 1.2274x over previous
//
#include <hip/hip_runtime.h>

// Problem constants
#define WW 256
#define NB 128      // batch N
#define CD 512      // channels
#define NE 8        // heads
#define HD 64       // head dim
#define NCHUNKS 4
#define SCALING 0.125f

typedef __attribute__((ext_vector_type(8))) short bfx8;
typedef __attribute__((ext_vector_type(4))) float fx4;

// workspace layout (float offsets)
#define OFF_MEAN   0u
#define OFF_RSTD   65536u
#define OFF_WPB    131072u          // 1536*512 bf16
#define OFF_OWB    524288u          // 512*512 bf16
#define OFF_S      655360u
#define OFF_U      656896u
#define OFF_PQ     658432u          // 511*512 bf16 (scaled q_r)
#define OFF_PK     789504u          // 511*512 bf16
#define OFF_QB     920576u          // 256*128*512 bf16
#define OFF_KB     9309184u
#define OFF_VB     17697792u
#define OFF_ATTN   26086400u        // 128*8*64*256 fp32 (flb/frb overlay pre-loop)
#define OFF_T3     42863616u        // 8*256*128*64 bf16
#define OFF_PB     51252224u        // 128*8*64*256 bf16 probs
#define OFF_VOB    59640832u        // 64*128*512 bf16
// total ~61.7M floats = 247 MB

// ---------------------------------------------------------------------------
__device__ __forceinline__ unsigned short f2bf(float f) {
  unsigned u = __builtin_bit_cast(unsigned, f);
  u = (u + 0x7fffu + ((u >> 16) & 1u)) >> 16;
  return (unsigned short)u;
}
__device__ __forceinline__ float bf2f(unsigned short h) {
  unsigned u = ((unsigned)h) << 16;
  return __builtin_bit_cast(float, u);
}

#define GLDS16(g, l)                                                          \
  __builtin_amdgcn_global_load_lds(                                           \
      (const __attribute__((address_space(1))) void*)(g),                     \
      (__attribute__((address_space(3))) void*)(l), 16, 0, 0)

// ---------------------------------------------------------------------------
// fp32 -> bf16 convert (used for out_w only)
__global__ __launch_bounds__(256) void cvt_kernel(const float* __restrict__ a,
                                                  unsigned short* __restrict__ b,
                                                  int n8) {
  int i = blockIdx.x * 256 + threadIdx.x;
  if (i >= n8) return;
  float4 x = ((const float4*)a)[2 * i];
  float4 y = ((const float4*)a)[2 * i + 1];
  int4 o;
  o.x = (int)(((unsigned)f2bf(x.y) << 16) | f2bf(x.x));
  o.y = (int)(((unsigned)f2bf(x.w) << 16) | f2bf(x.z));
  o.z = (int)(((unsigned)f2bf(y.y) << 16) | f2bf(y.x));
  o.w = (int)(((unsigned)f2bf(y.w) << 16) | f2bf(y.z));
  ((int4*)b)[i] = o;
}

// ---------------------------------------------------------------------------
// Row stats for LN folding, fused with fp32->bf16 conversion of fl/fr.
__global__ __launch_bounds__(256) void stats_kernel(const float* __restrict__ L,
                                                    const float* __restrict__ R,
                                                    float* __restrict__ mean,
                                                    float* __restrict__ rstd,
                                                    unsigned short* __restrict__ flb,
                                                    unsigned short* __restrict__ frb) {
  int wave = threadIdx.x >> 6, lane = threadIdx.x & 63;
  int row = blockIdx.x * 4 + wave;
  const float* src = (row < 32768) ? (L + (size_t)row * CD) : (R + (size_t)(row - 32768) * CD);
  unsigned short* drow = (row < 32768) ? (flb + (size_t)row * CD) : (frb + (size_t)(row - 32768) * CD);
  float4 a = *(const float4*)(src + lane * 4);
  float4 b = *(const float4*)(src + 256 + lane * 4);
  short4 sa, sb;
  sa.x = (short)f2bf(a.x); sa.y = (short)f2bf(a.y); sa.z = (short)f2bf(a.z); sa.w = (short)f2bf(a.w);
  sb.x = (short)f2bf(b.x); sb.y = (short)f2bf(b.y); sb.z = (short)f2bf(b.z); sb.w = (short)f2bf(b.w);
  *(short4*)(drow + lane * 4) = sa;
  *(short4*)(drow + 256 + lane * 4) = sb;
  float s  = a.x + a.y + a.z + a.w + b.x + b.y + b.z + b.w;
  float ss = a.x*a.x + a.y*a.y + a.z*a.z + a.w*a.w + b.x*b.x + b.y*b.y + b.z*b.z + b.w*b.w;
#pragma unroll
  for (int off = 32; off > 0; off >>= 1) {
    s  += __shfl_xor(s, off);
    ss += __shfl_xor(ss, off);
  }
  if (lane == 0) {
    float m = s * (1.0f / 512.0f);
    float v = ss * (1.0f / 512.0f) - m * m;
    mean[row] = m;
    rstd[row] = rsqrtf(v + 1e-5f);
  }
}

// ---------------------------------------------------------------------------
// Fold ln_w into in_proj_w (bf16); per-output-row constants S,U.
__global__ __launch_bounds__(256) void prep_kernel(const float* __restrict__ ipw,
                                                   const float* __restrict__ ipb,
                                                   const float* __restrict__ lnw,
                                                   const float* __restrict__ lnb,
                                                   unsigned short* __restrict__ Wpb,
                                                   float* __restrict__ S,
                                                   float* __restrict__ U) {
  int o = blockIdx.x, t = threadIdx.x;
  float s = 0.f, u = 0.f;
#pragma unroll
  for (int j0 = 0; j0 < 512; j0 += 256) {
    int j = j0 + t;
    float w0 = ipw[(size_t)o * 512 + j];
    float wl = w0 * lnw[j];
    unsigned short h = f2bf(wl);
    Wpb[(size_t)o * 512 + j] = h;
    s += bf2f(h);
    u += w0 * lnb[j];
  }
  __shared__ float rs[4], ru[4];
  int lane = t & 63, wv = t >> 6;
#pragma unroll
  for (int off = 32; off > 0; off >>= 1) { s += __shfl_xor(s, off); u += __shfl_xor(u, off); }
  if (lane == 0) { rs[wv] = s; ru[wv] = u; }
  __syncthreads();
  if (t == 0) {
    S[o] = rs[0] + rs[1] + rs[2] + rs[3];
    U[o] = ru[0] + ru[1] + ru[2] + ru[3] + ipb[o];
  }
}

// ---------------------------------------------------------------------------
// bf16 MFMA GEMM with LN-fold epilogue, bf16 output.
// grid: x = m-tiles (fast axis -> same A-tile consumers share an XCD), y = n-tiles
__global__ __launch_bounds__(256) void gemm_ln(const unsigned short* __restrict__ A,
                                               const unsigned short* __restrict__ Bw,
                                               const float* __restrict__ S,
                                               const float* __restrict__ U,
                                               const float* __restrict__ mean,
                                               const float* __restrict__ rstd,
                                               unsigned short* __restrict__ out0,
                                               unsigned short* __restrict__ out1,
                                               int wOff, int statOff, float scale) {
  __shared__ unsigned short As[128 * 32];
  __shared__ unsigned short Bs[128 * 32];
  int t = threadIdx.x;
  int lane = t & 63, w = t >> 6;
  int quad = lane >> 4, l15 = lane & 15;
  int wm = w >> 1, wn = w & 1;
  int m0 = blockIdx.x * 128, n0 = blockIdx.y * 128;

  unsigned short* ldsA0 = As + (size_t)w * 16 * 32;
  unsigned short* ldsA1 = As + (size_t)(64 + w * 16) * 32;
  unsigned short* ldsB0 = Bs + (size_t)w * 16 * 32;
  unsigned short* ldsB1 = Bs + (size_t)(64 + w * 16) * 32;
  const unsigned short* gA0 = A + (size_t)(m0 + w * 16 + (lane >> 2)) * 512 + (lane & 3) * 8;
  const unsigned short* gA1 = gA0 + (size_t)64 * 512;
  const unsigned short* gB0 = Bw + (size_t)(wOff + n0 + w * 16 + (lane >> 2)) * 512 + (lane & 3) * 8;
  const unsigned short* gB1 = gB0 + (size_t)64 * 512;

  fx4 acc[4][4];
#pragma unroll
  for (int i = 0; i < 4; ++i)
#pragma unroll
    for (int j = 0; j < 4; ++j) acc[i][j] = (fx4){0.f, 0.f, 0.f, 0.f};

  for (int kt = 0; kt < 512; kt += 32) {
    GLDS16(gA0 + kt, ldsA0);
    GLDS16(gA1 + kt, ldsA1);
    GLDS16(gB0 + kt, ldsB0);
    GLDS16(gB1 + kt, ldsB1);
    __syncthreads();
    bfx8 af[4], bfr[4];
#pragma unroll
    for (int i = 0; i < 4; ++i)
      af[i] = *(const bfx8*)(As + (size_t)(wm * 64 + i * 16 + l15) * 32 + quad * 8);
#pragma unroll
    for (int j = 0; j < 4; ++j)
      bfr[j] = *(const bfx8*)(Bs + (size_t)(wn * 64 + j * 16 + l15) * 32 + quad * 8);
#pragma unroll
    for (int i = 0; i < 4; ++i)
#pragma unroll
      for (int j = 0; j < 4; ++j)
        acc[i][j] = __builtin_amdgcn_mfma_f32_16x16x32_bf16(af[i], bfr[j], acc[i][j], 0, 0, 0);
    __syncthreads();
  }

  float mn[16], rs[16];
#pragma unroll
  for (int i = 0; i < 4; ++i)
#pragma unroll
    for (int r = 0; r < 4; ++r) {
      int m = statOff + m0 + wm * 64 + i * 16 + quad * 4 + r;
      mn[i * 4 + r] = mean[m];
      rs[i * 4 + r] = rstd[m];
    }
#pragma unroll
  for (int j = 0; j < 4; ++j) {
    int oc = n0 + wn * 64 + j * 16 + l15;
    int o = wOff + oc;
    float Sv = S[o], Uv = U[o];
    unsigned short* dst; int cc;
    if (oc < 512) { dst = out0; cc = oc; } else { dst = out1; cc = oc - 512; }
#pragma unroll
    for (int i = 0; i < 4; ++i)
#pragma unroll
      for (int r = 0; r < 4; ++r) {
        int m = m0 + wm * 64 + i * 16 + quad * 4 + r;
        dst[(size_t)m * 512 + cc] =
            f2bf(((acc[i][j][r] - mn[i * 4 + r] * Sv) * rs[i * 4 + r] + Uv) * scale);
      }
  }
}

// ---------------------------------------------------------------------------
// bf16 MFMA GEMM out-proj: out[g,o] = fl[g,o] + sum_j vob[m,j]*owb[o,j] + ob[o]
__global__ __launch_bounds__(256) void gemm_out(const unsigned short* __restrict__ A,
                                                const unsigned short* __restrict__ Bw,
                                                const float* __restrict__ ob,
                                                const float* __restrict__ fl,
                                                float* __restrict__ out, int wc) {
  __shared__ unsigned short As[128 * 32];
  __shared__ unsigned short Bs[128 * 32];
  int t = threadIdx.x;
  int lane = t & 63, w = t >> 6;
  int quad = lane >> 4, l15 = lane & 15;
  int wm = w >> 1, wn = w & 1;
  int n0 = blockIdx.x * 128, m0 = blockIdx.y * 128;

  unsigned short* ldsA0 = As + (size_t)w * 16 * 32;
  unsigned short* ldsA1 = As + (size_t)(64 + w * 16) * 32;
  unsigned short* ldsB0 = Bs + (size_t)w * 16 * 32;
  unsigned short* ldsB1 = Bs + (size_t)(64 + w * 16) * 32;
  const unsigned short* gA0 = A + (size_t)(m0 + w * 16 + (lane >> 2)) * 512 + (lane & 3) * 8;
  const unsigned short* gA1 = gA0 + (size_t)64 * 512;
  const unsigned short* gB0 = Bw + (size_t)(n0 + w * 16 + (lane >> 2)) * 512 + (lane & 3) * 8;
  const unsigned short* gB1 = gB0 + (size_t)64 * 512;

  fx4 acc[4][4];
#pragma unroll
  for (int i = 0; i < 4; ++i)
#pragma unroll
    for (int j = 0; j < 4; ++j) acc[i][j] = (fx4){0.f, 0.f, 0.f, 0.f};

  for (int kt = 0; kt < 512; kt += 32) {
    GLDS16(gA0 + kt, ldsA0);
    GLDS16(gA1 + kt, ldsA1);
    GLDS16(gB0 + kt, ldsB0);
    GLDS16(gB1 + kt, ldsB1);
    __syncthreads();
    bfx8 af[4], bfr[4];
#pragma unroll
    for (int i = 0; i < 4; ++i)
      af[i] = *(const bfx8*)(As + (size_t)(wm * 64 + i * 16 + l15) * 32 + quad * 8);
#pragma unroll
    for (int j = 0; j < 4; ++j)
      bfr[j] = *(const bfx8*)(Bs + (size_t)(wn * 64 + j * 16 + l15) * 32 + quad * 8);
#pragma unroll
    for (int i = 0; i < 4; ++i)
#pragma unroll
      for (int j = 0; j < 4; ++j)
        acc[i][j] = __builtin_amdgcn_mfma_f32_16x16x32_bf16(af[i], bfr[j], acc[i][j], 0, 0, 0);
    __syncthreads();
  }

  size_t gbase = (size_t)wc * 64 * NB * CD;
#pragma unroll
  for (int j = 0; j < 4; ++j) {
    int o = n0 + wn * 64 + j * 16 + l15;
    float bias = ob[o];
#pragma unroll
    for (int i = 0; i < 4; ++i)
#pragma unroll
      for (int r = 0; r < 4; ++r) {
        int m = m0 + wm * 64 + i * 16 + quad * 4 + r;
        size_t go = gbase + (size_t)m * 512 + o;
        out[go] = acc[i][j][r] + bias + fl[go];
      }
  }
}

// ---------------------------------------------------------------------------
// fp32 helper for posproj only
__device__ __forceinline__ void compute16(const float* __restrict__ As,
                                          const float* __restrict__ Bs,
                                          float acc[4][4], int tx, int ty) {
#pragma unroll
  for (int kk = 0; kk < 16; ++kk) {
    float4 av = *(const float4*)(As + kk * 64 + ty * 4);
    float4 bv = *(const float4*)(Bs + kk * 64 + tx * 4);
    const float aa[4] = {av.x, av.y, av.z, av.w};
    const float bb[4] = {bv.x, bv.y, bv.z, bv.w};
#pragma unroll
    for (int i = 0; i < 4; ++i)
#pragma unroll
      for (int j = 0; j < 4; ++j)
        acc[i][j] = fmaf(aa[i], bb[j], acc[i][j]);
  }
}

// pos table projection (NO layernorm) — fp32 compute, bf16 out, tiny
__global__ __launch_bounds__(256) void posproj_kernel(const float* __restrict__ pos,
                                                      const float* __restrict__ ipw,
                                                      const float* __restrict__ ipb,
                                                      unsigned short* __restrict__ Pq,
                                                      unsigned short* __restrict__ Pk) {
  __shared__ float As[16 * 64], Bs[16 * 64];
  int t = threadIdx.x, tx = t & 15, ty = t >> 4;
  int n0 = blockIdx.x * 64, m0 = blockIdx.y * 64;
  int lr = t >> 2, lq = t & 3;
  int arow = m0 + lr; if (arow > 510) arow = 510;
  const float* xrow = pos + (size_t)arow * 512 + lq * 4;
  const float* wrow = ipw + (size_t)(n0 + lr) * 512 + lq * 4;
  float acc[4][4] = {};
  for (int kt = 0; kt < 512; kt += 16) {
    float4 a = *(const float4*)(xrow + kt);
    float4 b = *(const float4*)(wrow + kt);
    __syncthreads();
    As[(lq * 4 + 0) * 64 + lr] = a.x; As[(lq * 4 + 1) * 64 + lr] = a.y;
    As[(lq * 4 + 2) * 64 + lr] = a.z; As[(lq * 4 + 3) * 64 + lr] = a.w;
    Bs[(lq * 4 + 0) * 64 + lr] = b.x; Bs[(lq * 4 + 1) * 64 + lr] = b.y;
    Bs[(lq * 4 + 2) * 64 + lr] = b.z; Bs[(lq * 4 + 3) * 64 + lr] = b.w;
    __syncthreads();
    compute16(As, Bs, acc, tx, ty);
  }
  float scale = (n0 < 512) ? SCALING : 1.0f;
  unsigned short* dst; int co;
  if (n0 < 512) { dst = Pq; co = n0; } else { dst = Pk; co = n0 - 512; }
#pragma unroll
  for (int i = 0; i < 4; ++i) {
    int m = m0 + ty * 4 + i;
    if (m < 511) {
      short4 r;
      r.x = (short)f2bf((acc[i][0] + ipb[n0 + tx * 4 + 0]) * scale);
      r.y = (short)f2bf((acc[i][1] + ipb[n0 + tx * 4 + 1]) * scale);
      r.z = (short)f2bf((acc[i][2] + ipb[n0 + tx * 4 + 2]) * scale);
      r.w = (short)f2bf((acc[i][3] + ipb[n0 + tx * 4 + 3]) * scale);
      *(short4*)(dst + (size_t)m * 512 + co + tx * 4) = r;
    }
  }
}

// ---------------------------------------------------------------------------
// term3 (bf16 MFMA): T3[e][v][n][wq] = sum_h k[v,n,e,h] * q_r[wq,v,e,h]
// grid: x=e(8), y=v(256); 4 waves, wave w = n-rows w*32..w*32+31
__global__ __launch_bounds__(256) void t3_kernel(const unsigned short* __restrict__ kb,
                                                 const unsigned short* __restrict__ Pq,
                                                 const int* __restrict__ idx,
                                                 unsigned short* __restrict__ T3, int wc) {
  __shared__ unsigned short As[128 * 72];
  __shared__ unsigned short Bs[64 * 72];
  int t = threadIdx.x, lane = t & 63, w = t >> 6;
  int quad = lane >> 4, l15 = lane & 15;
  int e = blockIdx.x, v = blockIdx.y;
  const unsigned short* asrc = kb + ((size_t)v * NB) * 512 + e * 64;
  for (int c = t; c < 1024; c += 256) {
    int row = c >> 3, c8 = c & 7;
    *(int4*)(As + row * 72 + c8 * 8) = *(const int4*)(asrc + (size_t)row * 512 + c8 * 8);
  }
  for (int c = t; c < 512; c += 256) {
    int row = c >> 3, c8 = c & 7;
    int ri = idx[(wc * 64 + row) * WW + v];
    *(int4*)(Bs + row * 72 + c8 * 8) = *(const int4*)(Pq + (size_t)ri * 512 + e * 64 + c8 * 8);
  }
  __syncthreads();
  fx4 acc[2][4];
#pragma unroll
  for (int i = 0; i < 2; ++i)
#pragma unroll
    for (int j = 0; j < 4; ++j) acc[i][j] = (fx4){0.f, 0.f, 0.f, 0.f};
#pragma unroll
  for (int kt = 0; kt < 64; kt += 32) {
    bfx8 af[2], bfr[4];
#pragma unroll
    for (int i = 0; i < 2; ++i)
      af[i] = *(const bfx8*)(As + (w * 32 + i * 16 + l15) * 72 + kt + quad * 8);
#pragma unroll
    for (int j = 0; j < 4; ++j)
      bfr[j] = *(const bfx8*)(Bs + (j * 16 + l15) * 72 + kt + quad * 8);
#pragma unroll
    for (int i = 0; i < 2; ++i)
#pragma unroll
      for (int j = 0; j < 4; ++j)
        acc[i][j] = __builtin_amdgcn_mfma_f32_16x16x32_bf16(af[i], bfr[j], acc[i][j], 0, 0, 0);
  }
#pragma unroll
  for (int i = 0; i < 2; ++i)
#pragma unroll
    for (int j = 0; j < 4; ++j)
#pragma unroll
      for (int r = 0; r < 4; ++r) {
        int n = w * 32 + i * 16 + quad * 4 + r;
        int wq = j * 16 + l15;
        T3[(((size_t)e * WW + v) * NB + n) * 64 + wq] = f2bf(acc[i][j][r]);
      }
}

// ---------------------------------------------------------------------------
// transpose T3(bf16) into attn(fp32) layout — first writer of attn
__global__ __launch_bounds__(256) void trans_kernel(const unsigned short* __restrict__ T3,
                                                    float* __restrict__ attn) {
  __shared__ unsigned short Ts[64 * 66];
  int t = threadIdx.x;
  int vt = blockIdx.x, e = blockIdx.y, n = blockIdx.z;
  int a = t & 63, g = t >> 6;
  const unsigned short* src = T3 + (((size_t)e * WW + vt * 64) * NB + n) * 64;
#pragma unroll
  for (int it = 0; it < 16; ++it) {
    int vv = g + it * 4;
    Ts[vv * 66 + a] = src[(size_t)vv * NB * 64 + a];
  }
  __syncthreads();
  float* dst = attn + (((size_t)n * NE + e) * 64) * WW + vt * 64;
#pragma unroll
  for (int it = 0; it < 16; ++it) {
    int wq = g + it * 4;
    dst[(size_t)wq * WW + a] = bf2f(Ts[a * 66 + wq]);
  }
}

// ---------------------------------------------------------------------------
// term1 (bf16 MFMA): attn[n,e,wq,v] += sum_h q[wq,n,e,h]*k[v,n,e,h]
// grid: x=e(8), y=n(128); 4 waves, wave w = v-range w*64
__global__ __launch_bounds__(256) void t1_kernel(const unsigned short* __restrict__ qb,
                                                 const unsigned short* __restrict__ kb,
                                                 float* __restrict__ attn, int wc) {
  __shared__ unsigned short As[64 * 72];
  __shared__ unsigned short Bs[256 * 72];
  int t = threadIdx.x, lane = t & 63, w = t >> 6;
  int quad = lane >> 4, l15 = lane & 15;
  int e = blockIdx.x, n = blockIdx.y;
  const unsigned short* asrc = qb + ((size_t)(wc * 64) * NB + n) * 512 + e * 64;
  for (int c = t; c < 512; c += 256) {
    int row = c >> 3, c8 = c & 7;
    *(int4*)(As + row * 72 + c8 * 8) = *(const int4*)(asrc + (size_t)row * NB * 512 + c8 * 8);
  }
  const unsigned short* bsrc = kb + (size_t)n * 512 + e * 64;
  for (int c = t; c < 2048; c += 256) {
    int row = c >> 3, c8 = c & 7;
    *(int4*)(Bs + row * 72 + c8 * 8) = *(const int4*)(bsrc + (size_t)row * NB * 512 + c8 * 8);
  }
  __syncthreads();
  fx4 acc[4][4];
#pragma unroll
  for (int i = 0; i < 4; ++i)
#pragma unroll
    for (int j = 0; j < 4; ++j) acc[i][j] = (fx4){0.f, 0.f, 0.f, 0.f};
#pragma unroll
  for (int kt = 0; kt < 64; kt += 32) {
    bfx8 af[4], bfr[4];
#pragma unroll
    for (int i = 0; i < 4; ++i)
      af[i] = *(const bfx8*)(As + (i * 16 + l15) * 72 + kt + quad * 8);
#pragma unroll
    for (int j = 0; j < 4; ++j)
      bfr[j] = *(const bfx8*)(Bs + (w * 64 + j * 16 + l15) * 72 + kt + quad * 8);
#pragma unroll
    for (int i = 0; i < 4; ++i)
#pragma unroll
      for (int j = 0; j < 4; ++j)
        acc[i][j] = __builtin_amdgcn_mfma_f32_16x16x32_bf16(af[i], bfr[j], acc[i][j], 0, 0, 0);
  }
#pragma unroll
  for (int i = 0; i < 4; ++i)
#pragma unroll
    for (int j = 0; j < 4; ++j)
#pragma unroll
      for (int r = 0; r < 4; ++r) {
        int wq = i * 16 + quad * 4 + r;
        int vg = w * 64 + j * 16 + l15;
        float* p = attn + (((size_t)n * NE + e) * 64 + wq) * WW + vg;
        *p += acc[i][j][r];
      }
}

// ---------------------------------------------------------------------------
// term2 (bf16 MFMA): attn[n,e,wq,v] += sum_h q[wq,n,e,h]*k_r[wq,v,e,h]
// grid: x=nt(2), y=e(8), z=wq(64); 4 waves, wave w = v-range w*64
__global__ __launch_bounds__(256) void t2_kernel(const unsigned short* __restrict__ qb,
                                                 const unsigned short* __restrict__ Pk,
                                                 const int* __restrict__ idx,
                                                 float* __restrict__ attn, int wc) {
  __shared__ unsigned short As[64 * 72];
  __shared__ unsigned short Bs[256 * 72];
  int t = threadIdx.x, lane = t & 63, w = t >> 6;
  int quad = lane >> 4, l15 = lane & 15;
  int nt = blockIdx.x, e = blockIdx.y, wq = blockIdx.z;
  const unsigned short* asrc = qb + ((size_t)(wc * 64 + wq) * NB + nt * 64) * 512 + e * 64;
  for (int c = t; c < 512; c += 256) {
    int row = c >> 3, c8 = c & 7;
    *(int4*)(As + row * 72 + c8 * 8) = *(const int4*)(asrc + (size_t)row * 512 + c8 * 8);
  }
  for (int c = t; c < 2048; c += 256) {
    int row = c >> 3, c8 = c & 7;
    int ri = idx[(wc * 64 + wq) * WW + row];
    *(int4*)(Bs + row * 72 + c8 * 8) = *(const int4*)(Pk + (size_t)ri * 512 + e * 64 + c8 * 8);
  }
  __syncthreads();
  fx4 acc[4][4];
#pragma unroll
  for (int i = 0; i < 4; ++i)
#pragma unroll
    for (int j = 0; j < 4; ++j) acc[i][j] = (fx4){0.f, 0.f, 0.f, 0.f};
#pragma unroll
  for (int kt = 0; kt < 64; kt += 32) {
    bfx8 af[4], bfr[4];
#pragma unroll
    for (int i = 0; i < 4; ++i)
      af[i] = *(const bfx8*)(As + (i * 16 + l15) * 72 + kt + quad * 8);
#pragma unroll
    for (int j = 0; j < 4; ++j)
      bfr[j] = *(const bfx8*)(Bs + (w * 64 + j * 16 + l15) * 72 + kt + quad * 8);
#pragma unroll
    for (int i = 0; i < 4; ++i)
#pragma unroll
      for (int j = 0; j < 4; ++j)
        acc[i][j] = __builtin_amdgcn_mfma_f32_16x16x32_bf16(af[i], bfr[j], acc[i][j], 0, 0, 0);
  }
#pragma unroll
  for (int i = 0; i < 4; ++i)
#pragma unroll
    for (int j = 0; j < 4; ++j)
#pragma unroll
      for (int r = 0; r < 4; ++r) {
        int nn = nt * 64 + i * 16 + quad * 4 + r;
        int vg = w * 64 + j * 16 + l15;
        float* p = attn + (((size_t)nn * NE + e) * 64 + wq) * WW + vg;
        *p += acc[i][j][r];
      }
}

// ---------------------------------------------------------------------------
// raw-sum over e + softmax over v; probs emitted as bf16 into pb
__device__ __forceinline__ float blk_max(float x, float* red, int t) {
#pragma unroll
  for (int off = 32; off > 0; off >>= 1) x = fmaxf(x, __shfl_xor(x, off));
  __syncthreads();
  if ((t & 63) == 0) red[t >> 6] = x;
  __syncthreads();
  return fmaxf(fmaxf(red[0], red[1]), fmaxf(red[2], red[3]));
}
__device__ __forceinline__ float blk_sum(float x, float* red, int t) {
#pragma unroll
  for (int off = 32; off > 0; off >>= 1) x += __shfl_xor(x, off);
  __syncthreads();
  if ((t & 63) == 0) red[t >> 6] = x;
  __syncthreads();
  return red[0] + red[1] + red[2] + red[3];
}

__global__ __launch_bounds__(256) void soft_kernel(const float* __restrict__ attn,
                                                   unsigned short* __restrict__ pb,
                                                   float* __restrict__ raw, int wc) {
  __shared__ float red[4];
  int t = threadIdx.x;
  int wq = blockIdx.x, n = blockIdx.y;
  float rows[NE]; float rsum = 0.f;
  const float* base = attn + (((size_t)n * NE) * 64 + wq) * WW + t;
#pragma unroll
  for (int e = 0; e < NE; ++e) { rows[e] = base[(size_t)e * 64 * WW]; rsum += rows[e]; }
  raw[((size_t)n * WW + wc * 64 + wq) * WW + t] = rsum;
  unsigned short* pbase = pb + (((size_t)n * NE) * 64 + wq) * WW + t;
#pragma unroll
  for (int e = 0; e < NE; ++e) {
    float m = blk_max(rows[e], red, t);
    float ex = __expf(rows[e] - m);
    float s = blk_sum(ex, red, t);
    pbase[(size_t)e * 64 * WW] = f2bf(ex / s);
  }
}

// ---------------------------------------------------------------------------
// PV (bf16 MFMA): vob[wq][n][e*64+h] = sum_v p[n,e,wq,v]*v[v,n,e,h]
// grid: x=e(8), y=n(128); 4 waves, wave w = wq-rows w*16..w*16+15; K-loop over v
__global__ __launch_bounds__(256) void pv_kernel(const unsigned short* __restrict__ pb,
                                                 const unsigned short* __restrict__ vb,
                                                 unsigned short* __restrict__ vob) {
  __shared__ unsigned short As[64 * 72];
  __shared__ unsigned short Bs[64 * 72];
  int t = threadIdx.x, lane = t & 63, w = t >> 6;
  int quad = lane >> 4, l15 = lane & 15;
  int e = blockIdx.x, n = blockIdx.y;
  fx4 acc[4];
#pragma unroll
  for (int j = 0; j < 4; ++j) acc[j] = (fx4){0.f, 0.f, 0.f, 0.f};
  const unsigned short* abase = pb + (((size_t)n * NE + e) * 64) * WW;
  for (int kc = 0; kc < 4; ++kc) {
    for (int c = t; c < 512; c += 256) {
      int row = c >> 3, c8 = c & 7;
      *(int4*)(As + row * 72 + c8 * 8) = *(const int4*)(abase + (size_t)row * WW + kc * 64 + c8 * 8);
    }
    for (int c = t; c < 512; c += 256) {
      int row = c >> 3, c8 = c & 7;
      *(int4*)(Bs + row * 72 + c8 * 8) =
          *(const int4*)(vb + ((size_t)(kc * 64 + row) * NB + n) * 512 + e * 64 + c8 * 8);
    }
    __syncthreads();
#pragma unroll
    for (int kt = 0; kt < 64; kt += 32) {
      bfx8 af = *(const bfx8*)(As + (w * 16 + l15) * 72 + kt + quad * 8);
      bfx8 bfr[4];
#pragma unroll
      for (int j = 0; j < 4; ++j)
        bfr[j] = *(const bfx8*)(Bs + (j * 16 + l15) * 72 + kt + quad * 8);
#pragma unroll
      for (int j = 0; j < 4; ++j)
        acc[j] = __builtin_amdgcn_mfma_f32_16x16x32_bf16(af, bfr[j], acc[j], 0, 0, 0);
    }
    __syncthreads();
  }
#pragma unroll
  for (int j = 0; j < 4; ++j)
#pragma unroll
    for (int r = 0; r < 4; ++r) {
      int wq = w * 16 + quad * 4 + r;
      vob[((size_t)wq * NB + n) * 512 + e * 64 + j * 16 + l15] = f2bf(acc[j][r]);
    }
}

// ---------------------------------------------------------------------------
extern "C" void kernel_launch(void* const* d_in, const int* in_sizes, int n_in,
                              void* d_out, int out_size, void* d_ws, size_t ws_size,
                              hipStream_t stream) {
  const float* fl  = (const float*)d_in[0];
  const float* fr  = (const float*)d_in[1];
  const float* pos = (const float*)d_in[2];
  const int*  pidx = (const int*)d_in[3];
  const float* lnw = (const float*)d_in[4];
  const float* lnb = (const float*)d_in[5];
  const float* ipw = (const float*)d_in[6];
  const float* ipb = (const float*)d_in[7];
  const float* ow  = (const float*)d_in[8];
  const float* ob  = (const float*)d_in[9];

  float* ws   = (float*)d_ws;
  float* mean = ws + OFF_MEAN;
  float* rstd = ws + OFF_RSTD;
  unsigned short* Wpb = (unsigned short*)(ws + OFF_WPB);
  unsigned short* owb = (unsigned short*)(ws + OFF_OWB);
  float* S    = ws + OFF_S;
  float* U    = ws + OFF_U;
  unsigned short* Pq = (unsigned short*)(ws + OFF_PQ);
  unsigned short* Pk = (unsigned short*)(ws + OFF_PK);
  unsigned short* qb = (unsigned short*)(ws + OFF_QB);
  unsigned short* kb = (unsigned short*)(ws + OFF_KB);
  unsigned short* vb = (unsigned short*)(ws + OFF_VB);
  float* attn = ws + OFF_ATTN;
  unsigned short* T3  = (unsigned short*)(ws + OFF_T3);
  unsigned short* pb  = (unsigned short*)(ws + OFF_PB);
  unsigned short* vob = (unsigned short*)(ws + OFF_VOB);
  // bf16 staging overlays (consumed by gemm_ln before chunk loop writes attn)
  unsigned short* flb = (unsigned short*)(ws + OFF_ATTN);
  unsigned short* frb = flb + (size_t)32768 * 512;

  float* outF = (float*)d_out;                       // [W][N][C]
  float* outR = outF + (size_t)WW * NB * CD;         // raw_attn [N][W][W]

  stats_kernel<<<16384, 256, 0, stream>>>(fl, fr, mean, rstd, flb, frb);
  prep_kernel<<<1536, 256, 0, stream>>>(ipw, ipb, lnw, lnb, Wpb, S, U);
  cvt_kernel<<<128, 256, 0, stream>>>(ow, owb, 32768);
  posproj_kernel<<<dim3(16, 8), 256, 0, stream>>>(pos, ipw, ipb, Pq, Pk);
  gemm_ln<<<dim3(256, 4), 256, 0, stream>>>(flb, Wpb, S, U, mean, rstd, qb, qb, 0, 0, SCALING);
  gemm_ln<<<dim3(256, 8), 256, 0, stream>>>(frb, Wpb, S, U, mean, rstd, kb, vb, 512, 32768, 1.0f);

  for (int wc = 0; wc < NCHUNKS; ++wc) {
    t3_kernel<<<dim3(8, 256), 256, 0, stream>>>(kb, Pq, pidx, T3, wc);
    trans_kernel<<<dim3(4, 8, 128), 256, 0, stream>>>(T3, attn);
    t1_kernel<<<dim3(8, 128), 256, 0, stream>>>(qb, kb, attn, wc);
    t2_kernel<<<dim3(2, 8, 64), 256, 0, stream>>>(qb, Pk, pidx, attn, wc);
    soft_kernel<<<dim3(64, 128), 256, 0, stream>>>(attn, pb, outR, wc);
    pv_kernel<<<dim3(8, 128), 256, 0, stream>>>(pb, vb, vob);
    gemm_out<<<dim3(4, 64), 256, 0, stream>>>(vob, owb, ob, fl, outF, wc);
  }
}